// Round 7
// baseline (810.785 us; speedup 1.0000x reference)
//
#include <hip/hip_runtime.h>
#include <stdint.h>

#define B 64
#define T 100
#define IN_F 700
#define RED 256
#define WID 4096
#define CLS 20
#define BT (B*T)                   // 6400
#define NELEM (BT*WID)             // 26,214,400
#define LOGITS_OFF 0
#define SPIKES_OFF (B*CLS)         // 1280
#define DRIVE_OFF (SPIKES_OFF + NELEM)

// ---- ws layout (floats) ----
#define WS_SLOTS 0                            // 3 u32
#define WS_W2Q 16                             // 20*4096
#define WS_XP  (WS_W2Q + CLS*WID)             // 6400*256
#define WS_CO  (WS_XP + BT*RED)               // 6400*256
#define WS_WEIGHTED (WS_CO + BT*RED)          // 64*4096

// ---- scratch inside d_out's spikes region (consumed before spikes written) ----
#define SC_WST 0                              // 700*256   transposed q4(spatial_W)
#define SC_W1T (SC_WST + IN_F*RED)            // 256*4096  transposed q4(fc1_W)
#define SC_CWT (SC_W1T + RED*WID)             // 1280*256  conv_W as [h][ic][o]

__host__ __device__ __forceinline__ uint32_t rotl32(uint32_t v, int r) {
  return (v << r) | (v >> (32 - r));
}

// JAX threefry2x32 (20 rounds), bit-exact.
__host__ __device__ __forceinline__ void threefry2x32(uint32_t k0, uint32_t k1,
                                                      uint32_t x0, uint32_t x1,
                                                      uint32_t& o0, uint32_t& o1) {
  uint32_t k2 = k0 ^ k1 ^ 0x1BD11BDAu;
  x0 += k0; x1 += k1;
#define TF_R(r) { x0 += x1; x1 = rotl32(x1, (r)); x1 ^= x0; }
  TF_R(13) TF_R(15) TF_R(26) TF_R(6)
  x0 += k1; x1 += k2 + 1u;
  TF_R(17) TF_R(29) TF_R(16) TF_R(24)
  x0 += k2; x1 += k0 + 2u;
  TF_R(13) TF_R(15) TF_R(26) TF_R(6)
  x0 += k0; x1 += k1 + 3u;
  TF_R(17) TF_R(29) TF_R(16) TF_R(24)
  x0 += k1; x1 += k2 + 4u;
  TF_R(13) TF_R(15) TF_R(26) TF_R(6)
  x0 += k2; x1 += k0 + 5u;
#undef TF_R
  o0 = x0; o1 = x1;
}

__global__ void absmax_kernel(const float* __restrict__ w, int n, uint32_t* slot) {
  __shared__ uint32_t sm[256];
  uint32_t m = 0u;
  for (int i = blockIdx.x * 256 + threadIdx.x; i < n; i += gridDim.x * 256)
    m = max(m, __float_as_uint(fabsf(w[i])));
  sm[threadIdx.x] = m;
  __syncthreads();
  for (int s = 128; s > 0; s >>= 1) {
    if (threadIdx.x < s) sm[threadIdx.x] = max(sm[threadIdx.x], sm[threadIdx.x + s]);
    __syncthreads();
  }
  if (threadIdx.x == 0) atomicMax(slot, sm[0]);
}

// quantize (identical per-element float ops) + transpose w[Nn][Kk] -> qT[Kk][Nn],
// LDS-tiled so BOTH global sides are coalesced (old version wrote one float per
// 16KB stride for fc1_W -> ~64 cache lines per wave).
__global__ __launch_bounds__(256)
void quant_t_kernel(const float* __restrict__ w, float* __restrict__ qT,
                    int Nn, int Kk, const uint32_t* __restrict__ slot) {
  __shared__ float tile[32][33];
  float s = fmaxf(__uint_as_float(*slot) / 7.0f, 1e-8f);
  int tx = threadIdx.x & 31, ty = threadIdx.x >> 5;   // 32 x 8
  int k0 = blockIdx.x * 32, n0 = blockIdx.y * 32;
#pragma unroll
  for (int r = 0; r < 32; r += 8) {
    int n = n0 + ty + r, k = k0 + tx;
    if (n < Nn && k < Kk) {
      float v = w[(size_t)n * Kk + k];
      tile[ty + r][tx] = rintf(v / s) * s;
    }
  }
  __syncthreads();
#pragma unroll
  for (int r = 0; r < 32; r += 8) {
    int k = k0 + ty + r, n = n0 + tx;
    if (k < Kk && n < Nn) qT[(size_t)k * Nn + n] = tile[tx][ty + r];
  }
}

__global__ void quant_kernel(const float* __restrict__ w, float* __restrict__ q,
                             int n, const uint32_t* __restrict__ slot) {
  float s = fmaxf(__uint_as_float(*slot) / 7.0f, 1e-8f);
  int i = blockIdx.x * 256 + threadIdx.x;
  if (i < n) q[i] = rintf(w[i] / s) * s;
}

// conv_W [o][ic][h] -> [h*256+ic][o]  (k-major with h outer, ic inner: matches
// the verified accumulation order)
__global__ void convw_t_kernel(const float* __restrict__ w, float* __restrict__ wt) {
  int id = blockIdx.x * 256 + threadIdx.x;   // < 256*1280
  if (id < 256 * 1280) {
    int o = id / 1280, r = id - o * 1280;
    int ic = r / 5, h = r - ic * 5;
    wt[(size_t)((h << 8) + ic) * 256 + o] = w[id];
  }
}

// Double-buffered small-N GEMM: 32x64 tile, ONE wave (64 threads), TM=8 TN=4.
// LDS floats/FMA = (8+4)/32 = 0.375 (vs gemm32's 0.75) -> halves the LDS-pipe
// demand that bounded the spatial/conv stages. 800 blocks keep 3+ waves/CU;
// the staging latency at this low TLP is hidden by reg-staged double buffering
// (issue next tile's global loads BEFORE compute, ds_write after - the barrier
// drain then happens after compute has covered the HBM/L2 latency).
// SRCA=0: A row-major [M][K]. SRCA=1: A is xp[BT][RED], k=(h*256+ic) im2col
// fold (identical values, identical ascending-k fmaf chain per output).
template<int SRCA>
__global__ __launch_bounds__(64, 2)
void gemmdb_kernel(const float* __restrict__ A, const float* __restrict__ Bt,
                   const float* __restrict__ bias, float* __restrict__ C,
                   int M, int N, int K) {
  constexpr int ASR = 36, BSR = 68;
  __shared__ float As[2][32 * ASR];   // 2 x 4.6 KB
  __shared__ float Bs[2][32 * BSR];   // 2 x 8.7 KB
  int tid = threadIdx.x;              // 0..63
  int tx = tid & 15, ty = tid >> 4;   // cols tx*4, rows ty*8..+7
  int m0 = blockIdx.x * 32, n0 = blockIdx.y * 64;
  int am = tid >> 3, ak4 = (tid & 7) << 2;   // A-stage: +rep*8 rows, k-off ak4
  float acc[32];
#pragma unroll
  for (int i = 0; i < 32; ++i) acc[i] = 0.f;

  float4 rA[4], rB[8];
  int nt = (K + 31) >> 5;

#define LOAD_TILE(kt_, klen_)                                                   \
  {                                                                             \
    int kt = (kt_), klen = (klen_);                                             \
    _Pragma("unroll")                                                           \
    for (int rep = 0; rep < 4; ++rep) {                                         \
      int m = rep * 8 + am;                                                     \
      float4 av = make_float4(0.f, 0.f, 0.f, 0.f);                              \
      if (ak4 < klen) {                                                         \
        if (SRCA == 0) {                                                        \
          av = *(const float4*)&A[(size_t)(m0 + m) * K + kt + ak4];             \
        } else {                                                                \
          int k = kt + ak4;                                                     \
          int h = k >> 8, ic = k & 255;                                         \
          int bt = m0 + m;                                                      \
          int b = bt / T, t = bt - b * T;                                       \
          int tt = t + h - 2;                                                   \
          if (tt >= 0 && tt < T)                                                \
            av = *(const float4*)&A[((size_t)(b * T + tt)) * RED + ic];         \
        }                                                                       \
      }                                                                         \
      rA[rep] = av;                                                             \
    }                                                                           \
    _Pragma("unroll")                                                           \
    for (int rep = 0; rep < 8; ++rep) {                                         \
      int e = rep * 64 + tid;                                                   \
      int kk = e >> 4, n4 = (e & 15) << 2;                                      \
      float4 v = make_float4(0.f, 0.f, 0.f, 0.f);                               \
      if (kk < klen) v = *(const float4*)&Bt[(size_t)(kt + kk) * N + n0 + n4];  \
      rB[rep] = v;                                                              \
    }                                                                           \
  }

#define WRITE_TILE(buf_)                                                        \
  {                                                                             \
    int buf = (buf_);                                                           \
    _Pragma("unroll")                                                           \
    for (int rep = 0; rep < 4; ++rep) {                                         \
      int m = rep * 8 + am;                                                     \
      As[buf][(ak4 + 0) * ASR + m] = rA[rep].x;                                 \
      As[buf][(ak4 + 1) * ASR + m] = rA[rep].y;                                 \
      As[buf][(ak4 + 2) * ASR + m] = rA[rep].z;                                 \
      As[buf][(ak4 + 3) * ASR + m] = rA[rep].w;                                 \
    }                                                                           \
    _Pragma("unroll")                                                           \
    for (int rep = 0; rep < 8; ++rep) {                                         \
      int e = rep * 64 + tid;                                                   \
      int kk = e >> 4, n4 = (e & 15) << 2;                                      \
      *(float4*)&Bs[buf][kk * BSR + n4] = rB[rep];                              \
    }                                                                           \
  }

  // prologue: tile 0
  {
    int klen0 = K < 32 ? K : 32;
    LOAD_TILE(0, klen0)
    WRITE_TILE(0)
  }
  __syncthreads();

  int cur = 0;
  for (int it = 0; it < nt; ++it) {
    int klen = K - it * 32; if (klen > 32) klen = 32;
    bool has_next = (it + 1) < nt;
    if (has_next) {
      int ktn = (it + 1) * 32;
      int klenn = K - ktn; if (klenn > 32) klenn = 32;
      LOAD_TILE(ktn, klenn)
    }
    // compute on buffer cur
    if (klen == 32) {
#pragma unroll
      for (int kk = 0; kk < 32; ++kk) {
        float a[8], b[4];
#pragma unroll
        for (int i = 0; i < 8; ++i) a[i] = As[cur][kk * ASR + ty * 8 + i];
#pragma unroll
        for (int d = 0; d < 4; ++d) b[d] = Bs[cur][kk * BSR + tx * 4 + d];
#pragma unroll
        for (int j = 0; j < 8; ++j)
#pragma unroll
          for (int d = 0; d < 4; ++d)
            acc[j * 4 + d] = fmaf(a[j], b[d], acc[j * 4 + d]);
      }
    } else {
      for (int kk = 0; kk < klen; ++kk) {
        float a[8], b[4];
#pragma unroll
        for (int i = 0; i < 8; ++i) a[i] = As[cur][kk * ASR + ty * 8 + i];
#pragma unroll
        for (int d = 0; d < 4; ++d) b[d] = Bs[cur][kk * BSR + tx * 4 + d];
#pragma unroll
        for (int j = 0; j < 8; ++j)
#pragma unroll
          for (int d = 0; d < 4; ++d)
            acc[j * 4 + d] = fmaf(a[j], b[d], acc[j * 4 + d]);
      }
    }
    if (has_next) WRITE_TILE(cur ^ 1)
    __syncthreads();
    cur ^= 1;
  }
#undef LOAD_TILE
#undef WRITE_TILE

  float bv[4];
#pragma unroll
  for (int d = 0; d < 4; ++d) bv[d] = bias[n0 + tx * 4 + d];
#pragma unroll
  for (int j = 0; j < 8; ++j) {
    int m = m0 + ty * 8 + j;
    float o[4];
#pragma unroll
    for (int d = 0; d < 4; ++d) o[d] = fmaxf(acc[j * 4 + d] + bv[d], 0.0f);
    *(float4*)&C[(size_t)m * N + n0 + tx * 4] = make_float4(o[0], o[1], o[2], o[3]);
  }
}

// fc1: drive = softplus(co @ W1qT + b)*latent*|g|, M=6400 N=4096 K=256.
// R6 version (best measured: 254 us) - unchanged this round.
__global__ __launch_bounds__(256, 4)
void fc1_kernel(const float* __restrict__ A, const float* __restrict__ Bt,
                const float* __restrict__ bias, const float* __restrict__ latent,
                const float* __restrict__ gain, float* __restrict__ C,
                int K, int N) {
  constexpr int ASR = 132, BSR = 132;
  __shared__ float As[32 * ASR];   // 16896 B
  __shared__ float Bs[32 * BSR];   // 16896 B
  int tid = threadIdx.x;
  int tx = tid & 15, ty = tid >> 4;
  // bijective XCD swizzle: 1600 blocks = 8 XCDs x 200
  int wid = (blockIdx.x & 7) * 200 + (blockIdx.x >> 3);
  int bx = wid % 50, by = wid / 50;
  int m0 = bx * 128, n0 = by * 128;
  float2 acc2[32];
#pragma unroll
  for (int i = 0; i < 32; ++i) acc2[i] = make_float2(0.f, 0.f);

  for (int kt = 0; kt < K; kt += 32) {
    // stage A transposed to k-major: 128x32 float4 loads over 4 reps
#pragma unroll
    for (int rep = 0; rep < 4; ++rep) {
      int e = rep * 256 + tid;
      int k4 = (e & 7) << 2, m = e >> 3;
      const float4 v = *(const float4*)&A[(size_t)(m0 + m) * K + kt + k4];
      As[(k4 + 0) * ASR + m] = v.x;
      As[(k4 + 1) * ASR + m] = v.y;
      As[(k4 + 2) * ASR + m] = v.z;
      As[(k4 + 3) * ASR + m] = v.w;
    }
    // stage B: 32 k x 128 n = 4 float4 over 4 reps, coalesced along n
#pragma unroll
    for (int rep = 0; rep < 4; ++rep) {
      int e = rep * 256 + tid;
      int n4 = (e & 31) << 2, kk = e >> 5;
      float4 v = *(const float4*)&Bt[(size_t)(kt + kk) * N + n0 + n4];
      *(float4*)&Bs[kk * BSR + n4] = v;
    }
    __syncthreads();
#pragma unroll
    for (int kk = 0; kk < 32; ++kk) {
      float a[8];
#pragma unroll
      for (int i = 0; i < 8; ++i) a[i] = As[kk * ASR + ty * 8 + i];
      float2 b0 = *(const float2*)&Bs[kk * BSR + tx * 4];
      float2 b1 = *(const float2*)&Bs[kk * BSR + tx * 4 + 2];
      float2 b2 = *(const float2*)&Bs[kk * BSR + 64 + tx * 4];
      float2 b3 = *(const float2*)&Bs[kk * BSR + 64 + tx * 4 + 2];
#pragma unroll
      for (int j = 0; j < 8; ++j) {
        acc2[j * 4 + 0].x = fmaf(a[j], b0.x, acc2[j * 4 + 0].x);
        acc2[j * 4 + 0].y = fmaf(a[j], b0.y, acc2[j * 4 + 0].y);
        acc2[j * 4 + 1].x = fmaf(a[j], b1.x, acc2[j * 4 + 1].x);
        acc2[j * 4 + 1].y = fmaf(a[j], b1.y, acc2[j * 4 + 1].y);
        acc2[j * 4 + 2].x = fmaf(a[j], b2.x, acc2[j * 4 + 2].x);
        acc2[j * 4 + 2].y = fmaf(a[j], b2.y, acc2[j * 4 + 2].y);
        acc2[j * 4 + 3].x = fmaf(a[j], b3.x, acc2[j * 4 + 3].x);
        acc2[j * 4 + 3].y = fmaf(a[j], b3.y, acc2[j * 4 + 3].y);
      }
    }
    __syncthreads();
  }

  float g = fabsf(gain[0]);
  float bv[8];
#pragma unroll
  for (int d = 0; d < 4; ++d) {
    bv[d] = bias[n0 + tx * 4 + d];
    bv[4 + d] = bias[n0 + 64 + tx * 4 + d];
  }
#pragma unroll
  for (int j = 0; j < 8; ++j) {
    int bt = m0 + ty * 8 + j;
    int q = bt / T;
    float lat = latent[bt - q * T];
    float o[8];
    o[0] = acc2[j * 4 + 0].x; o[1] = acc2[j * 4 + 0].y;
    o[2] = acc2[j * 4 + 1].x; o[3] = acc2[j * 4 + 1].y;
    o[4] = acc2[j * 4 + 2].x; o[5] = acc2[j * 4 + 2].y;
    o[6] = acc2[j * 4 + 3].x; o[7] = acc2[j * 4 + 3].y;
#pragma unroll
    for (int d = 0; d < 8; ++d) {
      float v = o[d] + bv[d];
      float e = expf(-fabsf(v));
      float l = log1pf(e);
      float sp = fmaxf(v, 0.0f) + l;
      o[d] = (sp * lat) * g;
    }
    float4 o0 = make_float4(o[0], o[1], o[2], o[3]);
    float4 o1 = make_float4(o[4], o[5], o[6], o[7]);
    *(float4*)&C[(size_t)bt * N + n0 + tx * 4] = o0;
    *(float4*)&C[(size_t)bt * N + n0 + 64 + tx * 4] = o1;
  }
}

// Fused spike sampling + decay-weighted reduction, float4-vectorized.
__global__ __launch_bounds__(256) void spike_weighted_kernel(float* __restrict__ out,
                                                             float* __restrict__ wt,
                                                             uint32_t k0, uint32_t k1) {
  __shared__ float dec[128];
  int tid = threadIdx.x;
  if (tid < T) {
    float step = 2.0f / 99.0f;
    float a = step * (float)tid;
    dec[tid] = expf(a - 2.0f);
  }
  __syncthreads();
  int b = blockIdx.x >> 2;
  int w = ((blockIdx.x & 3) << 10) + (tid << 2);
  float acc0 = 0.f, acc1 = 0.f, acc2 = 0.f, acc3 = 0.f;
  for (int t = 0; t < T; ++t) {
    uint32_t p = (uint32_t)((b * T + t) * WID + w);
    float4 lam = *(const float4*)&out[DRIVE_OFF + p];
    float s[4];
#pragma unroll
    for (int i = 0; i < 4; ++i) {
      uint32_t y0, y1;
      threefry2x32(k0, k1, 0u, p + i, y0, y1);
      uint32_t bits = y0 ^ y1;
      float u = __uint_as_float((bits >> 9) | 0x3f800000u) - 1.0f;
      float lamv = (i == 0) ? lam.x : (i == 1) ? lam.y : (i == 2) ? lam.z : lam.w;
      s[i] = (lamv > 0.0f && logf(u) > -lamv) ? 1.0f : 0.0f;
    }
    *(float4*)&out[SPIKES_OFF + p] = make_float4(s[0], s[1], s[2], s[3]);
    float d = dec[t];
    acc0 = fmaf(s[0], d, acc0);
    acc1 = fmaf(s[1], d, acc1);
    acc2 = fmaf(s[2], d, acc2);
    acc3 = fmaf(s[3], d, acc3);
  }
  *(float4*)&wt[b * WID + w] = make_float4(acc0, acc1, acc2, acc3);
}

// logits[b,c] = sum_w weighted[b,w]*W2q[c,w] + b2[c]
__global__ void logits_kernel(const float* __restrict__ wt,
                              const float* __restrict__ w2,
                              const float* __restrict__ b2,
                              float* __restrict__ out) {
  __shared__ float sm[256];
  int b = blockIdx.x / CLS, c = blockIdx.x - b * CLS;
  const float* wr = wt + (size_t)b * WID;
  const float* w2r = w2 + (size_t)c * WID;
  float p = 0.f;
  for (int w = threadIdx.x; w < WID; w += 256) p = fmaf(wr[w], w2r[w], p);
  sm[threadIdx.x] = p;
  __syncthreads();
  for (int s = 128; s > 0; s >>= 1) {
    if (threadIdx.x < s) sm[threadIdx.x] += sm[threadIdx.x + s];
    __syncthreads();
  }
  if (threadIdx.x == 0) out[LOGITS_OFF + blockIdx.x] = sm[0] + b2[c];
}

extern "C" void kernel_launch(void* const* d_in, const int* in_sizes, int n_in,
                              void* d_out, int out_size, void* d_ws, size_t ws_size,
                              hipStream_t stream) {
  (void)in_sizes; (void)n_in; (void)out_size; (void)ws_size;
  const float* x         = (const float*)d_in[0];
  const float* latent    = (const float*)d_in[1];
  const float* spatial_W = (const float*)d_in[2];
  const float* spatial_b = (const float*)d_in[3];
  const float* conv_W    = (const float*)d_in[4];
  const float* conv_b    = (const float*)d_in[5];
  const float* fc1_W     = (const float*)d_in[6];
  const float* fc1_b     = (const float*)d_in[7];
  const float* fc2_W     = (const float*)d_in[8];
  const float* fc2_b     = (const float*)d_in[9];
  const float* gain      = (const float*)d_in[10];
  float* out = (float*)d_out;
  uint32_t* wsu = (uint32_t*)d_ws;
  float* wsf = (float*)d_ws;
  float* S = out + SPIKES_OFF;   // scratch in the not-yet-written spikes region

  // rng chain (partitionable split): subkey = full pair of threefry(rng0,(0,1))
  uint32_t sk0, sk1;
  threefry2x32(0u, 42u, 0u, 1u, sk0, sk1);

  hipMemsetAsync(wsu + WS_SLOTS, 0, 3 * sizeof(uint32_t), stream);
  absmax_kernel<<<64, 256, 0, stream>>>(spatial_W, RED * IN_F, wsu + WS_SLOTS + 0);
  absmax_kernel<<<256, 256, 0, stream>>>(fc1_W, WID * RED, wsu + WS_SLOTS + 1);
  absmax_kernel<<<32, 256, 0, stream>>>(fc2_W, CLS * WID, wsu + WS_SLOTS + 2);

  // tiled transposes: w[Nn][Kk] -> qT[Kk][Nn]; grid (ceil(Kk/32), ceil(Nn/32))
  quant_t_kernel<<<dim3(22, 8), 256, 0, stream>>>(spatial_W, S + SC_WST, RED, IN_F, wsu + WS_SLOTS + 0);
  quant_t_kernel<<<dim3(8, 128), 256, 0, stream>>>(fc1_W, S + SC_W1T, WID, RED, wsu + WS_SLOTS + 1);
  quant_kernel<<<320, 256, 0, stream>>>(fc2_W, wsf + WS_W2Q, CLS * WID, wsu + WS_SLOTS + 2);
  convw_t_kernel<<<1280, 256, 0, stream>>>(conv_W, S + SC_CWT);

  // spatial: xp = relu(x @ WsqT + b)   M=6400 N=256 K=700
  gemmdb_kernel<0><<<dim3(200, 4), 64, 0, stream>>>(
      x, S + SC_WST, spatial_b, wsf + WS_XP, BT, RED, IN_F);

  // conv: co = relu(conv1d(xp))  M=6400 N=256 K=1280, im2col folded into staging
  gemmdb_kernel<1><<<dim3(200, 4), 64, 0, stream>>>(
      wsf + WS_XP, S + SC_CWT, conv_b, wsf + WS_CO, BT, RED, 1280);

  // fc1: drive = softplus(co @ W1qT + b)*latent*|g|  M=6400 N=4096 K=256
  fc1_kernel<<<1600, 256, 0, stream>>>(
      wsf + WS_CO, S + SC_W1T, fc1_b, latent, gain, out + DRIVE_OFF, RED, WID);

  spike_weighted_kernel<<<B * 4, 256, 0, stream>>>(out, wsf + WS_WEIGHTED, sk0, sk1);

  logits_kernel<<<B * CLS, 256, 0, stream>>>(wsf + WS_WEIGHTED, wsf + WS_W2Q, fc2_b, out);
}

// Round 8
// 720.059 us; speedup vs baseline: 1.1260x; 1.1260x over previous
//
#include <hip/hip_runtime.h>
#include <stdint.h>

#define B 64
#define T 100
#define IN_F 700
#define RED 256
#define WID 4096
#define CLS 20
#define BT (B*T)                   // 6400
#define NELEM (BT*WID)             // 26,214,400
#define LOGITS_OFF 0
#define SPIKES_OFF (B*CLS)         // 1280
#define DRIVE_OFF (SPIKES_OFF + NELEM)

// ---- ws layout (floats) ----
#define WS_SLOTS 0                            // 3 u32
#define WS_W2Q 16                             // 20*4096
#define WS_XP  (WS_W2Q + CLS*WID)             // 6400*256
#define WS_CO  (WS_XP + BT*RED)               // 6400*256
#define WS_WEIGHTED (WS_CO + BT*RED)          // 64*4096

// ---- scratch inside d_out's spikes region (consumed before spikes written) ----
#define SC_WST 0                              // 700*256   transposed q4(spatial_W)
#define SC_W1T (SC_WST + IN_F*RED)            // 256*4096  transposed q4(fc1_W)
#define SC_CWT (SC_W1T + RED*WID)             // 1280*256  conv_W as [h][ic][o]

__host__ __device__ __forceinline__ uint32_t rotl32(uint32_t v, int r) {
  return (v << r) | (v >> (32 - r));
}

// JAX threefry2x32 (20 rounds), bit-exact.
__host__ __device__ __forceinline__ void threefry2x32(uint32_t k0, uint32_t k1,
                                                      uint32_t x0, uint32_t x1,
                                                      uint32_t& o0, uint32_t& o1) {
  uint32_t k2 = k0 ^ k1 ^ 0x1BD11BDAu;
  x0 += k0; x1 += k1;
#define TF_R(r) { x0 += x1; x1 = rotl32(x1, (r)); x1 ^= x0; }
  TF_R(13) TF_R(15) TF_R(26) TF_R(6)
  x0 += k1; x1 += k2 + 1u;
  TF_R(17) TF_R(29) TF_R(16) TF_R(24)
  x0 += k2; x1 += k0 + 2u;
  TF_R(13) TF_R(15) TF_R(26) TF_R(6)
  x0 += k0; x1 += k1 + 3u;
  TF_R(17) TF_R(29) TF_R(16) TF_R(24)
  x0 += k1; x1 += k2 + 4u;
  TF_R(13) TF_R(15) TF_R(26) TF_R(6)
  x0 += k2; x1 += k0 + 5u;
#undef TF_R
  o0 = x0; o1 = x1;
}

__global__ void absmax_kernel(const float* __restrict__ w, int n, uint32_t* slot) {
  __shared__ uint32_t sm[256];
  uint32_t m = 0u;
  for (int i = blockIdx.x * 256 + threadIdx.x; i < n; i += gridDim.x * 256)
    m = max(m, __float_as_uint(fabsf(w[i])));
  sm[threadIdx.x] = m;
  __syncthreads();
  for (int s = 128; s > 0; s >>= 1) {
    if (threadIdx.x < s) sm[threadIdx.x] = max(sm[threadIdx.x], sm[threadIdx.x + s]);
    __syncthreads();
  }
  if (threadIdx.x == 0) atomicMax(slot, sm[0]);
}

// quantize (identical per-element float ops) + transpose w[Nn][Kk] -> qT[Kk][Nn],
// LDS-tiled so BOTH global sides are coalesced (the scalar version wrote one
// float per 16KB stride for fc1_W -> ~64 cache lines touched per wave).
__global__ __launch_bounds__(256)
void quant_t_kernel(const float* __restrict__ w, float* __restrict__ qT,
                    int Nn, int Kk, const uint32_t* __restrict__ slot) {
  __shared__ float tile[32][33];
  float s = fmaxf(__uint_as_float(*slot) / 7.0f, 1e-8f);
  int tx = threadIdx.x & 31, ty = threadIdx.x >> 5;   // 32 x 8
  int k0 = blockIdx.x * 32, n0 = blockIdx.y * 32;
#pragma unroll
  for (int r = 0; r < 32; r += 8) {
    int n = n0 + ty + r, k = k0 + tx;
    if (n < Nn && k < Kk) {
      float v = w[(size_t)n * Kk + k];
      tile[ty + r][tx] = rintf(v / s) * s;
    }
  }
  __syncthreads();
#pragma unroll
  for (int r = 0; r < 32; r += 8) {
    int k = k0 + ty + r, n = n0 + tx;
    if (k < Kk && n < Nn) qT[(size_t)k * Nn + n] = tile[tx][ty + r];
  }
}

__global__ void quant_kernel(const float* __restrict__ w, float* __restrict__ q,
                             int n, const uint32_t* __restrict__ slot) {
  float s = fmaxf(__uint_as_float(*slot) / 7.0f, 1e-8f);
  int i = blockIdx.x * 256 + threadIdx.x;
  if (i < n) q[i] = rintf(w[i] / s) * s;
}

// conv_W [o][ic][h] -> [h*256+ic][o]  (k-major with h outer, ic inner: matches
// the verified accumulation order)
__global__ void convw_t_kernel(const float* __restrict__ w, float* __restrict__ wt) {
  int id = blockIdx.x * 256 + threadIdx.x;   // < 256*1280
  if (id < 256 * 1280) {
    int o = id / 1280, r = id - o * 1280;
    int ic = r / 5, h = r - ic * 5;
    wt[(size_t)((h << 8) + ic) * 256 + o] = w[id];
  }
}

// Small-N GEMM for the RED=256-wide stages: 32x64 tile, TM=2 TN=4, relu+bias.
// (R2's version — best measured for these stages.)
// SRCA=0: A is row-major [M][K].  SRCA=1: A is xp[BT][RED], k=(h*256+ic),
// i.e. the conv im2col is folded into the staging load (identical values and
// identical ascending-k accumulation order as a materialized im2col).
template<int SRCA>
__global__ __launch_bounds__(256, 8)
void gemm32_kernel(const float* __restrict__ A, const float* __restrict__ Bt,
                   const float* __restrict__ bias, float* __restrict__ C,
                   int M, int N, int K) {
  constexpr int MT = 32, NT = 64, TM = 2, TN = 4;
  constexpr int ASR = MT + 4, BSR = NT + 4;
  __shared__ float As[32 * ASR];
  __shared__ float Bs[32 * BSR];
  int tid = threadIdx.x;
  int tx = tid & 15, ty = tid >> 4;
  int m0 = blockIdx.x * MT, n0 = blockIdx.y * NT;
  int am = tid >> 3, ak4 = (tid & 7) << 2;       // A-stage: row am, k-offset ak4
  float acc[TM * TN];
#pragma unroll
  for (int i = 0; i < TM * TN; ++i) acc[i] = 0.f;

  for (int kt = 0; kt < K; kt += 32) {
    int klen = K - kt; if (klen > 32) klen = 32;
    // stage A (k-major): one float4 per thread (32 rows x 32 k)
    {
      float4 av = make_float4(0.f, 0.f, 0.f, 0.f);
      if (ak4 < klen) {
        if (SRCA == 0) {
          av = *(const float4*)&A[(size_t)(m0 + am) * K + kt + ak4];
        } else {
          int k = kt + ak4;
          int h = k >> 8, ic = k & 255;
          int bt = m0 + am;
          int b = bt / T, t = bt - b * T;
          int tt = t + h - 2;
          if (tt >= 0 && tt < T)
            av = *(const float4*)&A[((size_t)(b * T + tt)) * RED + ic];
        }
      }
      As[(ak4 + 0) * ASR + am] = av.x;
      As[(ak4 + 1) * ASR + am] = av.y;
      As[(ak4 + 2) * ASR + am] = av.z;
      As[(ak4 + 3) * ASR + am] = av.w;
    }
    // stage B: two float4 per thread (32 k x 64 n), coalesced along n
#pragma unroll
    for (int rep = 0; rep < 2; ++rep) {
      int e = rep * 256 + tid;
      int n4 = (e & 15) << 2, kk = e >> 4;
      float4 v = make_float4(0.f, 0.f, 0.f, 0.f);
      if (kk < klen) v = *(const float4*)&Bt[(size_t)(kt + kk) * N + n0 + n4];
      *(float4*)&Bs[kk * BSR + n4] = v;
    }
    __syncthreads();
    if (klen == 32) {
#pragma unroll
      for (int kk = 0; kk < 32; ++kk) {
        float a[TM], b[TN];
#pragma unroll
        for (int i = 0; i < TM; ++i) a[i] = As[kk * ASR + ty * TM + i];
#pragma unroll
        for (int d = 0; d < TN; ++d) b[d] = Bs[kk * BSR + tx * TN + d];
#pragma unroll
        for (int j = 0; j < TM; ++j)
#pragma unroll
          for (int d = 0; d < TN; ++d)
            acc[j * TN + d] = fmaf(a[j], b[d], acc[j * TN + d]);
      }
    } else {
      for (int kk = 0; kk < klen; ++kk) {
        float a[TM], b[TN];
#pragma unroll
        for (int i = 0; i < TM; ++i) a[i] = As[kk * ASR + ty * TM + i];
#pragma unroll
        for (int d = 0; d < TN; ++d) b[d] = Bs[kk * BSR + tx * TN + d];
#pragma unroll
        for (int j = 0; j < TM; ++j)
#pragma unroll
          for (int d = 0; d < TN; ++d)
            acc[j * TN + d] = fmaf(a[j], b[d], acc[j * TN + d]);
      }
    }
    __syncthreads();
  }

  float bv[TN];
#pragma unroll
  for (int d = 0; d < TN; ++d) bv[d] = bias[n0 + tx * TN + d];
#pragma unroll
  for (int j = 0; j < TM; ++j) {
    int m = m0 + ty * TM + j;
#pragma unroll
    for (int d = 0; d < TN; ++d)
      C[(size_t)m * N + n0 + tx * TN + d] = fmaxf(acc[j * TN + d] + bv[d], 0.0f);
  }
}

// fc1: drive = softplus(co @ W1qT + b)*latent*|g|, M=6400 N=4096 K=256.
// Restructured: 128x128 tile, 512 threads (8 waves), TM=8(m) x TN=4(n, split
// cols nx*2 and 64+nx*2). acc[32] + operands ~= 55 live regs -> fits the
// 64-VGPR arch file with NO AGPR tail (the suspected source of the 2x
// VALU-issue inflation seen at TM8xTN8 acc[64] for 3 rounds).
// LDS unchanged (33.8 KB): 4 blocks/CU = 32 waves possible.
// b-reads: 2x ds_read_b64, 32 distinct addrs -> 2 lanes/bank = free.
// a-reads: 2x ds_read_b128, 2 distinct addrs/wave -> broadcast, free.
// Per-output accumulation is fmaf over k ascending from 0 -> drive bit-exact.
__global__ __launch_bounds__(512, 4)
void fc1_kernel(const float* __restrict__ A, const float* __restrict__ Bt,
                const float* __restrict__ bias, const float* __restrict__ latent,
                const float* __restrict__ gain, float* __restrict__ C,
                int K, int N) {
  constexpr int ASR = 132, BSR = 132;
  __shared__ float As[32 * ASR];   // 16896 B
  __shared__ float Bs[32 * BSR];   // 16896 B
  int tid = threadIdx.x;
  int nx = tid & 31, my = tid >> 5;   // n-group 0..31, m-group 0..15
  // bijective XCD swizzle: 1600 blocks = 8 XCDs x 200
  int wid = (blockIdx.x & 7) * 200 + (blockIdx.x >> 3);
  int bx = wid % 50, by = wid / 50;
  int m0 = bx * 128, n0 = by * 128;
  float acc[32];
#pragma unroll
  for (int i = 0; i < 32; ++i) acc[i] = 0.f;

  for (int kt = 0; kt < K; kt += 32) {
    // stage A transposed to k-major: 128 rows x 32 k = 2 float4 per thread
#pragma unroll
    for (int rep = 0; rep < 2; ++rep) {
      int e = rep * 512 + tid;
      int k4 = (e & 7) << 2, m = e >> 3;
      const float4 v = *(const float4*)&A[(size_t)(m0 + m) * K + kt + k4];
      As[(k4 + 0) * ASR + m] = v.x;
      As[(k4 + 1) * ASR + m] = v.y;
      As[(k4 + 2) * ASR + m] = v.z;
      As[(k4 + 3) * ASR + m] = v.w;
    }
    // stage B: 32 k x 128 n = 2 float4 per thread, coalesced along n
#pragma unroll
    for (int rep = 0; rep < 2; ++rep) {
      int e = rep * 512 + tid;
      int n4 = (e & 31) << 2, kk = e >> 5;
      float4 v = *(const float4*)&Bt[(size_t)(kt + kk) * N + n0 + n4];
      *(float4*)&Bs[kk * BSR + n4] = v;
    }
    __syncthreads();
#pragma unroll
    for (int kk = 0; kk < 32; ++kk) {
      float a[8];
#pragma unroll
      for (int i = 0; i < 8; ++i) a[i] = As[kk * ASR + my * 8 + i];
      float2 b0 = *(const float2*)&Bs[kk * BSR + nx * 2];
      float2 b1 = *(const float2*)&Bs[kk * BSR + 64 + nx * 2];
      float b[4] = {b0.x, b0.y, b1.x, b1.y};
#pragma unroll
      for (int j = 0; j < 8; ++j)
#pragma unroll
        for (int d = 0; d < 4; ++d)
          acc[j * 4 + d] = fmaf(a[j], b[d], acc[j * 4 + d]);
    }
    __syncthreads();
  }

  float g = fabsf(gain[0]);
  float bv[4];
  bv[0] = bias[n0 + nx * 2];
  bv[1] = bias[n0 + nx * 2 + 1];
  bv[2] = bias[n0 + 64 + nx * 2];
  bv[3] = bias[n0 + 64 + nx * 2 + 1];
#pragma unroll
  for (int j = 0; j < 8; ++j) {
    int bt = m0 + my * 8 + j;
    int q = bt / T;
    float lat = latent[bt - q * T];
    float o[4];
#pragma unroll
    for (int d = 0; d < 4; ++d) {
      float v = acc[j * 4 + d] + bv[d];
      float e = expf(-fabsf(v));
      float l = log1pf(e);
      float sp = fmaxf(v, 0.0f) + l;
      o[d] = (sp * lat) * g;
    }
    *(float2*)&C[(size_t)bt * N + n0 + nx * 2] = make_float2(o[0], o[1]);
    *(float2*)&C[(size_t)bt * N + n0 + 64 + nx * 2] = make_float2(o[2], o[3]);
  }
}

// Fused spike sampling + decay-weighted reduction, float4-vectorized.
__global__ __launch_bounds__(256) void spike_weighted_kernel(float* __restrict__ out,
                                                             float* __restrict__ wt,
                                                             uint32_t k0, uint32_t k1) {
  __shared__ float dec[128];
  int tid = threadIdx.x;
  if (tid < T) {
    float step = 2.0f / 99.0f;
    float a = step * (float)tid;
    dec[tid] = expf(a - 2.0f);
  }
  __syncthreads();
  int b = blockIdx.x >> 2;
  int w = ((blockIdx.x & 3) << 10) + (tid << 2);
  float acc0 = 0.f, acc1 = 0.f, acc2 = 0.f, acc3 = 0.f;
  for (int t = 0; t < T; ++t) {
    uint32_t p = (uint32_t)((b * T + t) * WID + w);
    float4 lam = *(const float4*)&out[DRIVE_OFF + p];
    float s[4];
#pragma unroll
    for (int i = 0; i < 4; ++i) {
      uint32_t y0, y1;
      threefry2x32(k0, k1, 0u, p + i, y0, y1);
      uint32_t bits = y0 ^ y1;
      float u = __uint_as_float((bits >> 9) | 0x3f800000u) - 1.0f;
      float lamv = (i == 0) ? lam.x : (i == 1) ? lam.y : (i == 2) ? lam.z : lam.w;
      s[i] = (lamv > 0.0f && logf(u) > -lamv) ? 1.0f : 0.0f;
    }
    *(float4*)&out[SPIKES_OFF + p] = make_float4(s[0], s[1], s[2], s[3]);
    float d = dec[t];
    acc0 = fmaf(s[0], d, acc0);
    acc1 = fmaf(s[1], d, acc1);
    acc2 = fmaf(s[2], d, acc2);
    acc3 = fmaf(s[3], d, acc3);
  }
  *(float4*)&wt[b * WID + w] = make_float4(acc0, acc1, acc2, acc3);
}

// logits[b,c] = sum_w weighted[b,w]*W2q[c,w] + b2[c]
__global__ void logits_kernel(const float* __restrict__ wt,
                              const float* __restrict__ w2,
                              const float* __restrict__ b2,
                              float* __restrict__ out) {
  __shared__ float sm[256];
  int b = blockIdx.x / CLS, c = blockIdx.x - b * CLS;
  const float* wr = wt + (size_t)b * WID;
  const float* w2r = w2 + (size_t)c * WID;
  float p = 0.f;
  for (int w = threadIdx.x; w < WID; w += 256) p = fmaf(wr[w], w2r[w], p);
  sm[threadIdx.x] = p;
  __syncthreads();
  for (int s = 128; s > 0; s >>= 1) {
    if (threadIdx.x < s) sm[threadIdx.x] += sm[threadIdx.x + s];
    __syncthreads();
  }
  if (threadIdx.x == 0) out[LOGITS_OFF + blockIdx.x] = sm[0] + b2[c];
}

extern "C" void kernel_launch(void* const* d_in, const int* in_sizes, int n_in,
                              void* d_out, int out_size, void* d_ws, size_t ws_size,
                              hipStream_t stream) {
  (void)in_sizes; (void)n_in; (void)out_size; (void)ws_size;
  const float* x         = (const float*)d_in[0];
  const float* latent    = (const float*)d_in[1];
  const float* spatial_W = (const float*)d_in[2];
  const float* spatial_b = (const float*)d_in[3];
  const float* conv_W    = (const float*)d_in[4];
  const float* conv_b    = (const float*)d_in[5];
  const float* fc1_W     = (const float*)d_in[6];
  const float* fc1_b     = (const float*)d_in[7];
  const float* fc2_W     = (const float*)d_in[8];
  const float* fc2_b     = (const float*)d_in[9];
  const float* gain      = (const float*)d_in[10];
  float* out = (float*)d_out;
  uint32_t* wsu = (uint32_t*)d_ws;
  float* wsf = (float*)d_ws;
  float* S = out + SPIKES_OFF;   // scratch in the not-yet-written spikes region

  // rng chain (partitionable split): subkey = full pair of threefry(rng0,(0,1))
  uint32_t sk0, sk1;
  threefry2x32(0u, 42u, 0u, 1u, sk0, sk1);

  hipMemsetAsync(wsu + WS_SLOTS, 0, 3 * sizeof(uint32_t), stream);
  absmax_kernel<<<64, 256, 0, stream>>>(spatial_W, RED * IN_F, wsu + WS_SLOTS + 0);
  absmax_kernel<<<256, 256, 0, stream>>>(fc1_W, WID * RED, wsu + WS_SLOTS + 1);
  absmax_kernel<<<32, 256, 0, stream>>>(fc2_W, CLS * WID, wsu + WS_SLOTS + 2);

  // tiled transposes: w[Nn][Kk] -> qT[Kk][Nn]; grid (ceil(Kk/32), ceil(Nn/32))
  quant_t_kernel<<<dim3(22, 8), 256, 0, stream>>>(spatial_W, S + SC_WST, RED, IN_F, wsu + WS_SLOTS + 0);
  quant_t_kernel<<<dim3(8, 128), 256, 0, stream>>>(fc1_W, S + SC_W1T, WID, RED, wsu + WS_SLOTS + 1);
  quant_kernel<<<320, 256, 0, stream>>>(fc2_W, wsf + WS_W2Q, CLS * WID, wsu + WS_SLOTS + 2);
  convw_t_kernel<<<1280, 256, 0, stream>>>(conv_W, S + SC_CWT);

  // spatial: xp = relu(x @ WsqT + b)   M=6400 N=256 K=700
  gemm32_kernel<0><<<dim3(200, 4), 256, 0, stream>>>(
      x, S + SC_WST, spatial_b, wsf + WS_XP, BT, RED, IN_F);

  // conv: co = relu(conv1d(xp))  M=6400 N=256 K=1280, im2col folded into staging
  gemm32_kernel<1><<<dim3(200, 4), 256, 0, stream>>>(
      wsf + WS_XP, S + SC_CWT, conv_b, wsf + WS_CO, BT, RED, 1280);

  // fc1: drive = softplus(co @ W1qT + b)*latent*|g|  M=6400 N=4096 K=256
  fc1_kernel<<<1600, 512, 0, stream>>>(
      wsf + WS_CO, S + SC_W1T, fc1_b, latent, gain, out + DRIVE_OFF, RED, WID);

  spike_weighted_kernel<<<B * 4, 256, 0, stream>>>(out, wsf + WS_WEIGHTED, sk0, sk1);

  logits_kernel<<<B * CLS, 256, 0, stream>>>(wsf + WS_WEIGHTED, wsf + WS_W2Q, fc2_b, out);
}